// Round 1
// baseline (1358.037 us; speedup 1.0000x reference)
//
#include <hip/hip_runtime.h>
#include <math.h>

#define D1 3
#define D2 50
#define D3 15
#define D5 10
#define NC 6

// ---------------------------------------------------------------------------
// Kernel 1: fused edge MLP + node MLP per edge, scatter-add into x2sum/cnt.
// One thread = one edge. Weights are read with wave-uniform addresses so the
// compiler turns them into s_load (scalar cache) -> each MAC is one v_fmac.
// ---------------------------------------------------------------------------
__global__ __launch_bounds__(256) void edge_node_kernel(
    const float* __restrict__ x,
    const int*   __restrict__ ei,
    const float* __restrict__ ea,
    const float* __restrict__ ew1, const float* __restrict__ eb1,
    const float* __restrict__ ew2, const float* __restrict__ eb2,
    const float* __restrict__ nw1, const float* __restrict__ nb1,
    const float* __restrict__ nw2, const float* __restrict__ nb2,
    float* __restrict__ x2sum, float* __restrict__ cnt,
    int E)
{
    int e = blockIdx.x * blockDim.x + threadIdx.x;
    if (e >= E) return;

    int r = ei[e];
    int c = ei[E + e];

    float in9[9];
    in9[0] = x[3 * r + 0];
    in9[1] = x[3 * r + 1];
    in9[2] = x[3 * r + 2];
    float xc0 = x[3 * c + 0], xc1 = x[3 * c + 1], xc2 = x[3 * c + 2];
    in9[3] = xc0; in9[4] = xc1; in9[5] = xc2;
    in9[6] = ea[3 * e + 0];
    in9[7] = ea[3 * e + 1];
    in9[8] = ea[3 * e + 2];

    // edge MLP layer 1: 9 -> 50, ReLU
    float h[D2];
    #pragma unroll
    for (int j = 0; j < D2; ++j) {
        float a = eb1[j];
        #pragma unroll
        for (int k = 0; k < 9; ++k) a = fmaf(in9[k], ew1[k * D2 + j], a);
        h[j] = fmaxf(a, 0.0f);
    }

    // edge MLP layer 2: 50 -> 15
    float e2[D3];
    #pragma unroll
    for (int j = 0; j < D3; ++j) {
        float a = eb2[j];
        #pragma unroll
        for (int k = 0; k < D2; ++k) a = fmaf(h[k], ew2[k * D3 + j], a);
        e2[j] = a;
    }

    // node MLP layer 1: [x[col], e2] (18) -> 50, ReLU
    float h2[D2];
    #pragma unroll
    for (int j = 0; j < D2; ++j) {
        float a = nb1[j];
        a = fmaf(xc0, nw1[0 * D2 + j], a);
        a = fmaf(xc1, nw1[1 * D2 + j], a);
        a = fmaf(xc2, nw1[2 * D2 + j], a);
        #pragma unroll
        for (int k = 0; k < D3; ++k) a = fmaf(e2[k], nw1[(3 + k) * D2 + j], a);
        h2[j] = fmaxf(a, 0.0f);
    }

    // node MLP layer 2: 50 -> 15, scatter-add over row
    float* dst = x2sum + (size_t)r * D3;
    #pragma unroll
    for (int j = 0; j < D3; ++j) {
        float a = nb2[j];
        #pragma unroll
        for (int k = 0; k < D2; ++k) a = fmaf(h2[k], nw2[k * D3 + j], a);
        atomicAdd(&dst[j], a);
    }
    atomicAdd(&cnt[r], 1.0f);
}

// ---------------------------------------------------------------------------
// Kernel 2: per-graph sums of x2 and relu(x2). batch is sorted, so each graph
// is a contiguous node range found by binary search. One block per graph.
// Computes x2 = x2sum / max(cnt,1) on the fly (never materialized).
// ---------------------------------------------------------------------------
__global__ __launch_bounds__(256) void graph_sum_kernel(
    const float* __restrict__ x2sum, const float* __restrict__ cnt,
    const int* __restrict__ batch, int N,
    float* __restrict__ bx, float* __restrict__ brelu, float* __restrict__ ncnt)
{
    int b = blockIdx.x;

    // lower_bound(batch, b)
    int lo = 0, hi = N;
    while (lo < hi) { int m = (lo + hi) >> 1; if (batch[m] < b) lo = m + 1; else hi = m; }
    int start = lo;
    hi = N;
    while (lo < hi) { int m = (lo + hi) >> 1; if (batch[m] < b + 1) lo = m + 1; else hi = m; }
    int end = lo;

    float sx[D3], sr[D3];
    #pragma unroll
    for (int j = 0; j < D3; ++j) { sx[j] = 0.0f; sr[j] = 0.0f; }

    for (int i = start + (int)threadIdx.x; i < end; i += (int)blockDim.x) {
        float cv = cnt[i];
        float inv = 1.0f / fmaxf(cv, 1.0f);
        #pragma unroll
        for (int j = 0; j < D3; ++j) {
            float v = x2sum[(size_t)i * D3 + j] * inv;
            sx[j] += v;
            sr[j] += fmaxf(v, 0.0f);
        }
    }

    // wave-level reduce (wave = 64 lanes)
    #pragma unroll
    for (int j = 0; j < D3; ++j) {
        #pragma unroll
        for (int s = 32; s > 0; s >>= 1) {
            sx[j] += __shfl_down(sx[j], s);
            sr[j] += __shfl_down(sr[j], s);
        }
    }

    __shared__ float sm[4][2 * D3];
    int lane = threadIdx.x & 63, wid = threadIdx.x >> 6;
    if (lane == 0) {
        #pragma unroll
        for (int j = 0; j < D3; ++j) { sm[wid][j] = sx[j]; sm[wid][D3 + j] = sr[j]; }
    }
    __syncthreads();
    if (threadIdx.x < 2 * D3) {
        float v = sm[0][threadIdx.x] + sm[1][threadIdx.x] + sm[2][threadIdx.x] + sm[3][threadIdx.x];
        if (threadIdx.x < D3) bx[b * D3 + threadIdx.x] = v;
        else                  brelu[b * D3 + (threadIdx.x - D3)] = v;
    }
    if (threadIdx.x == 0) ncnt[b] = (float)(end - start);
}

// ---------------------------------------------------------------------------
// Kernel 3: global MLP + readout mean + FC head + BN(eval) + log_softmax.
// One thread per graph (B = 256).
// ---------------------------------------------------------------------------
__global__ __launch_bounds__(256) void final_kernel(
    const float* __restrict__ u,
    const float* __restrict__ gw1, const float* __restrict__ gb1,
    const float* __restrict__ gw2, const float* __restrict__ gb2,
    const float* __restrict__ fc1w, const float* __restrict__ fc1b,
    const float* __restrict__ bng, const float* __restrict__ bnb,
    const float* __restrict__ fc2w, const float* __restrict__ fc2b,
    const float* __restrict__ bx, const float* __restrict__ brelu,
    const float* __restrict__ ncnt,
    float* __restrict__ out, int B)
{
    int t = blockIdx.x * blockDim.x + threadIdx.x;
    if (t >= B) return;

    float nct = ncnt[t];
    float inv = 1.0f / fmaxf(nct, 1.0f);

    float in16[16];
    in16[0] = u[t];
    #pragma unroll
    for (int j = 0; j < D3; ++j) in16[1 + j] = bx[t * D3 + j] * inv;

    // global MLP layer 1: 16 -> 50, ReLU
    float gh[D2];
    #pragma unroll
    for (int j = 0; j < D2; ++j) {
        float a = gb1[j];
        #pragma unroll
        for (int k = 0; k < 16; ++k) a = fmaf(in16[k], gw1[k * D2 + j], a);
        gh[j] = fmaxf(a, 0.0f);
    }

    // global MLP layer 2: 50 -> 15; then readout mean g = (brelu + relu(u2)) / (n+1)
    float g[D3];
    #pragma unroll
    for (int j = 0; j < D3; ++j) {
        float a = gb2[j];
        #pragma unroll
        for (int k = 0; k < D2; ++k) a = fmaf(gh[k], gw2[k * D3 + j], a);
        g[j] = (brelu[t * D3 + j] + fmaxf(a, 0.0f)) / (nct + 1.0f);
    }

    // fc1 + BatchNorm(eval, mean=0,var=1) + ReLU
    const float bnscale = 1.0f / sqrtf(1.0f + 1e-5f);
    float h1[D5];
    #pragma unroll
    for (int i = 0; i < D5; ++i) {
        float a = fc1b[i];
        #pragma unroll
        for (int k = 0; k < D3; ++k) a = fmaf(g[k], fc1w[k * D5 + i], a);
        h1[i] = fmaxf(a * (bng[i] * bnscale) + bnb[i], 0.0f);
    }

    // fc2 + log_softmax
    float o[NC];
    #pragma unroll
    for (int j = 0; j < NC; ++j) {
        float a = fc2b[j];
        #pragma unroll
        for (int k = 0; k < D5; ++k) a = fmaf(h1[k], fc2w[k * NC + j], a);
        o[j] = a;
    }
    float m = o[0];
    #pragma unroll
    for (int j = 1; j < NC; ++j) m = fmaxf(m, o[j]);
    float ssum = 0.0f;
    #pragma unroll
    for (int j = 0; j < NC; ++j) ssum += expf(o[j] - m);
    float lse = m + logf(ssum);
    #pragma unroll
    for (int j = 0; j < NC; ++j) out[t * NC + j] = o[j] - lse;
}

extern "C" void kernel_launch(void* const* d_in, const int* in_sizes, int n_in,
                              void* d_out, int out_size, void* d_ws, size_t ws_size,
                              hipStream_t stream) {
    const float* x     = (const float*)d_in[0];
    const int*   ei    = (const int*)  d_in[1];
    const float* ea    = (const float*)d_in[2];
    const float* u     = (const float*)d_in[3];
    const int*   batch = (const int*)  d_in[4];
    const float* ew1 = (const float*)d_in[5];
    const float* eb1 = (const float*)d_in[6];
    const float* ew2 = (const float*)d_in[7];
    const float* eb2 = (const float*)d_in[8];
    const float* nw1 = (const float*)d_in[9];
    const float* nb1 = (const float*)d_in[10];
    const float* nw2 = (const float*)d_in[11];
    const float* nb2 = (const float*)d_in[12];
    const float* gw1 = (const float*)d_in[13];
    const float* gb1 = (const float*)d_in[14];
    const float* gw2 = (const float*)d_in[15];
    const float* gb2 = (const float*)d_in[16];
    const float* fc1w = (const float*)d_in[17];
    const float* fc1b = (const float*)d_in[18];
    const float* bng  = (const float*)d_in[19];
    const float* bnb  = (const float*)d_in[20];
    const float* fc2w = (const float*)d_in[21];
    const float* fc2b = (const float*)d_in[22];

    int N = in_sizes[0] / 3;
    int E = in_sizes[2] / 3;
    int B = in_sizes[3];
    float* out = (float*)d_out;

    // workspace layout
    float* x2sum = (float*)d_ws;                   // N * D3
    float* cnt   = x2sum + (size_t)N * D3;         // N
    float* bx    = cnt + N;                        // B * D3
    float* brelu = bx + (size_t)B * D3;            // B * D3
    float* ncnt  = brelu + (size_t)B * D3;         // B

    // zero the atomic accumulators each call (harness does not re-poison)
    hipMemsetAsync(x2sum, 0, sizeof(float) * ((size_t)N * D3 + N), stream);

    int blocks = (E + 255) / 256;
    edge_node_kernel<<<blocks, 256, 0, stream>>>(
        x, ei, ea, ew1, eb1, ew2, eb2, nw1, nb1, nw2, nb2, x2sum, cnt, E);

    graph_sum_kernel<<<B, 256, 0, stream>>>(x2sum, cnt, batch, N, bx, brelu, ncnt);

    int fb = (B + 255) / 256;
    final_kernel<<<fb, 256, 0, stream>>>(
        u, gw1, gb1, gw2, gb2, fc1w, fc1b, bng, bnb, fc2w, fc2b,
        bx, brelu, ncnt, out, B);
}

// Round 2
// 537.914 us; speedup vs baseline: 2.5246x; 2.5246x over previous
//
#include <hip/hip_runtime.h>
#include <math.h>

#define D1 3
#define D2 50
#define D3 15
#define D5 10
#define NC 6
#define SCAN_B 256

// ---------------------------------------------------------------------------
// Kernel A: degree + rank. One int atomic per edge; return value = rank of
// this edge within its destination node. 16x fewer atomics than round 1.
// ---------------------------------------------------------------------------
__global__ __launch_bounds__(256) void deg_rank_kernel(
    const int* __restrict__ ei, int* __restrict__ deg, int* __restrict__ rank, int E)
{
    int e = blockIdx.x * blockDim.x + threadIdx.x;
    if (e >= E) return;
    int r = ei[e];
    rank[e] = atomicAdd(&deg[r], 1);
}

// ---------------------------------------------------------------------------
// Exclusive scan of deg[N] -> base[N], 3-phase.
// ---------------------------------------------------------------------------
__global__ __launch_bounds__(SCAN_B) void scan1_kernel(
    const int* __restrict__ deg, int* __restrict__ base, int* __restrict__ bsum, int N)
{
    __shared__ int sm[SCAN_B];
    int i = blockIdx.x * SCAN_B + threadIdx.x;
    int v = (i < N) ? deg[i] : 0;
    sm[threadIdx.x] = v;
    __syncthreads();
    #pragma unroll
    for (int s = 1; s < SCAN_B; s <<= 1) {
        int t = (threadIdx.x >= s) ? sm[threadIdx.x - s] : 0;
        __syncthreads();
        sm[threadIdx.x] += t;
        __syncthreads();
    }
    if (i < N) base[i] = sm[threadIdx.x] - v;   // exclusive
    if (threadIdx.x == SCAN_B - 1) bsum[blockIdx.x] = sm[threadIdx.x];
}

__global__ __launch_bounds__(1024) void scan2_kernel(int* __restrict__ bsum, int nb)
{
    __shared__ int sm[1024];
    int v = ((int)threadIdx.x < nb) ? bsum[threadIdx.x] : 0;
    sm[threadIdx.x] = v;
    __syncthreads();
    #pragma unroll
    for (int s = 1; s < 1024; s <<= 1) {
        int t = (threadIdx.x >= s) ? sm[threadIdx.x - s] : 0;
        __syncthreads();
        sm[threadIdx.x] += t;
        __syncthreads();
    }
    if ((int)threadIdx.x < nb) bsum[threadIdx.x] = sm[threadIdx.x] - v; // exclusive
}

__global__ __launch_bounds__(SCAN_B) void scan3_kernel(
    int* __restrict__ base, const int* __restrict__ bsum, int N)
{
    int i = blockIdx.x * SCAN_B + threadIdx.x;
    if (i < N) base[i] += bsum[blockIdx.x];
}

// ---------------------------------------------------------------------------
// Kernel C: fused edge MLP + node MLP per edge, NO atomics. Writes the 15
// node-MLP outputs to hbuf at the CSR slot base[row]+rank[e].
// Weights read wave-uniformly -> s_load -> each MAC is one v_fmac.
// ---------------------------------------------------------------------------
__global__ __launch_bounds__(256) void edge_mlp_kernel(
    const float* __restrict__ x,
    const int*   __restrict__ ei,
    const float* __restrict__ ea,
    const float* __restrict__ ew1, const float* __restrict__ eb1,
    const float* __restrict__ ew2, const float* __restrict__ eb2,
    const float* __restrict__ nw1, const float* __restrict__ nb1,
    const float* __restrict__ nw2, const float* __restrict__ nb2,
    const int* __restrict__ base, const int* __restrict__ rank,
    float* __restrict__ hbuf,
    int E)
{
    int e = blockIdx.x * blockDim.x + threadIdx.x;
    if (e >= E) return;

    int r = ei[e];
    int c = ei[E + e];

    float in9[9];
    in9[0] = x[3 * r + 0];
    in9[1] = x[3 * r + 1];
    in9[2] = x[3 * r + 2];
    float xc0 = x[3 * c + 0], xc1 = x[3 * c + 1], xc2 = x[3 * c + 2];
    in9[3] = xc0; in9[4] = xc1; in9[5] = xc2;
    in9[6] = ea[3 * e + 0];
    in9[7] = ea[3 * e + 1];
    in9[8] = ea[3 * e + 2];

    // edge MLP layer 1: 9 -> 50, ReLU
    float h[D2];
    #pragma unroll
    for (int j = 0; j < D2; ++j) {
        float a = eb1[j];
        #pragma unroll
        for (int k = 0; k < 9; ++k) a = fmaf(in9[k], ew1[k * D2 + j], a);
        h[j] = fmaxf(a, 0.0f);
    }

    // edge MLP layer 2: 50 -> 15
    float e2[D3];
    #pragma unroll
    for (int j = 0; j < D3; ++j) {
        float a = eb2[j];
        #pragma unroll
        for (int k = 0; k < D2; ++k) a = fmaf(h[k], ew2[k * D3 + j], a);
        e2[j] = a;
    }

    // node MLP layer 1: [x[col], e2] (18) -> 50, ReLU
    float h2[D2];
    #pragma unroll
    for (int j = 0; j < D2; ++j) {
        float a = nb1[j];
        a = fmaf(xc0, nw1[0 * D2 + j], a);
        a = fmaf(xc1, nw1[1 * D2 + j], a);
        a = fmaf(xc2, nw1[2 * D2 + j], a);
        #pragma unroll
        for (int k = 0; k < D3; ++k) a = fmaf(e2[k], nw1[(3 + k) * D2 + j], a);
        h2[j] = fmaxf(a, 0.0f);
    }

    // node MLP layer 2: 50 -> 15, plain store to CSR slot
    int slot = base[r] + rank[e];
    float* dst = hbuf + (size_t)slot * D3;
    #pragma unroll
    for (int j = 0; j < D3; ++j) {
        float a = nb2[j];
        #pragma unroll
        for (int k = 0; k < D2; ++k) a = fmaf(h2[k], nw2[k * D3 + j], a);
        dst[j] = a;
    }
}

// ---------------------------------------------------------------------------
// Kernel D: CSR gather. Thread = (node, dim). Sums hbuf over the node's
// contiguous segment, divides by max(deg,1) -> x2.
// ---------------------------------------------------------------------------
__global__ __launch_bounds__(256) void gather_kernel(
    const float* __restrict__ hbuf, const int* __restrict__ deg,
    const int* __restrict__ base, float* __restrict__ x2, int N)
{
    int idx = blockIdx.x * blockDim.x + threadIdx.x;
    if (idx >= N * D3) return;
    int n = idx / D3;
    int j = idx - n * D3;
    int b = base[n];
    int d = deg[n];
    float s = 0.0f;
    for (int k = 0; k < d; ++k) s += hbuf[(size_t)(b + k) * D3 + j];
    x2[(size_t)n * D3 + j] = s / fmaxf((float)d, 1.0f);
}

// ---------------------------------------------------------------------------
// Kernel E: per-graph sums of x2 and relu(x2). batch sorted -> contiguous
// ranges via binary search; one block per graph.
// ---------------------------------------------------------------------------
__global__ __launch_bounds__(256) void graph_sum_x2_kernel(
    const float* __restrict__ x2,
    const int* __restrict__ batch, int N,
    float* __restrict__ bx, float* __restrict__ brelu, float* __restrict__ ncnt)
{
    int b = blockIdx.x;

    int lo = 0, hi = N;
    while (lo < hi) { int m = (lo + hi) >> 1; if (batch[m] < b) lo = m + 1; else hi = m; }
    int start = lo;
    hi = N;
    while (lo < hi) { int m = (lo + hi) >> 1; if (batch[m] < b + 1) lo = m + 1; else hi = m; }
    int end = lo;

    float sx[D3], sr[D3];
    #pragma unroll
    for (int j = 0; j < D3; ++j) { sx[j] = 0.0f; sr[j] = 0.0f; }

    for (int i = start + (int)threadIdx.x; i < end; i += (int)blockDim.x) {
        #pragma unroll
        for (int j = 0; j < D3; ++j) {
            float v = x2[(size_t)i * D3 + j];
            sx[j] += v;
            sr[j] += fmaxf(v, 0.0f);
        }
    }

    #pragma unroll
    for (int j = 0; j < D3; ++j) {
        #pragma unroll
        for (int s = 32; s > 0; s >>= 1) {
            sx[j] += __shfl_down(sx[j], s);
            sr[j] += __shfl_down(sr[j], s);
        }
    }

    __shared__ float sm[4][2 * D3];
    int lane = threadIdx.x & 63, wid = threadIdx.x >> 6;
    if (lane == 0) {
        #pragma unroll
        for (int j = 0; j < D3; ++j) { sm[wid][j] = sx[j]; sm[wid][D3 + j] = sr[j]; }
    }
    __syncthreads();
    if (threadIdx.x < 2 * D3) {
        float v = sm[0][threadIdx.x] + sm[1][threadIdx.x] + sm[2][threadIdx.x] + sm[3][threadIdx.x];
        if (threadIdx.x < D3) bx[b * D3 + threadIdx.x] = v;
        else                  brelu[b * D3 + (threadIdx.x - D3)] = v;
    }
    if (threadIdx.x == 0) ncnt[b] = (float)(end - start);
}

// ---------------------------------------------------------------------------
// Kernel F: global MLP + readout mean + FC head + BN(eval) + log_softmax.
// ---------------------------------------------------------------------------
__global__ __launch_bounds__(256) void final_kernel(
    const float* __restrict__ u,
    const float* __restrict__ gw1, const float* __restrict__ gb1,
    const float* __restrict__ gw2, const float* __restrict__ gb2,
    const float* __restrict__ fc1w, const float* __restrict__ fc1b,
    const float* __restrict__ bng, const float* __restrict__ bnb,
    const float* __restrict__ fc2w, const float* __restrict__ fc2b,
    const float* __restrict__ bx, const float* __restrict__ brelu,
    const float* __restrict__ ncnt,
    float* __restrict__ out, int B)
{
    int t = blockIdx.x * blockDim.x + threadIdx.x;
    if (t >= B) return;

    float nct = ncnt[t];
    float inv = 1.0f / fmaxf(nct, 1.0f);

    float in16[16];
    in16[0] = u[t];
    #pragma unroll
    for (int j = 0; j < D3; ++j) in16[1 + j] = bx[t * D3 + j] * inv;

    float gh[D2];
    #pragma unroll
    for (int j = 0; j < D2; ++j) {
        float a = gb1[j];
        #pragma unroll
        for (int k = 0; k < 16; ++k) a = fmaf(in16[k], gw1[k * D2 + j], a);
        gh[j] = fmaxf(a, 0.0f);
    }

    float g[D3];
    #pragma unroll
    for (int j = 0; j < D3; ++j) {
        float a = gb2[j];
        #pragma unroll
        for (int k = 0; k < D2; ++k) a = fmaf(gh[k], gw2[k * D3 + j], a);
        g[j] = (brelu[t * D3 + j] + fmaxf(a, 0.0f)) / (nct + 1.0f);
    }

    const float bnscale = 1.0f / sqrtf(1.0f + 1e-5f);
    float h1[D5];
    #pragma unroll
    for (int i = 0; i < D5; ++i) {
        float a = fc1b[i];
        #pragma unroll
        for (int k = 0; k < D3; ++k) a = fmaf(g[k], fc1w[k * D5 + i], a);
        h1[i] = fmaxf(a * (bng[i] * bnscale) + bnb[i], 0.0f);
    }

    float o[NC];
    #pragma unroll
    for (int j = 0; j < NC; ++j) {
        float a = fc2b[j];
        #pragma unroll
        for (int k = 0; k < D5; ++k) a = fmaf(h1[k], fc2w[k * NC + j], a);
        o[j] = a;
    }
    float m = o[0];
    #pragma unroll
    for (int j = 1; j < NC; ++j) m = fmaxf(m, o[j]);
    float ssum = 0.0f;
    #pragma unroll
    for (int j = 0; j < NC; ++j) ssum += expf(o[j] - m);
    float lse = m + logf(ssum);
    #pragma unroll
    for (int j = 0; j < NC; ++j) out[t * NC + j] = o[j] - lse;
}

// ---------------------------------------------------------------------------
// Fallback (round-1) kernels: atomic scatter-mean. Used only if ws too small.
// ---------------------------------------------------------------------------
__global__ __launch_bounds__(256) void edge_node_atomic_kernel(
    const float* __restrict__ x,
    const int*   __restrict__ ei,
    const float* __restrict__ ea,
    const float* __restrict__ ew1, const float* __restrict__ eb1,
    const float* __restrict__ ew2, const float* __restrict__ eb2,
    const float* __restrict__ nw1, const float* __restrict__ nb1,
    const float* __restrict__ nw2, const float* __restrict__ nb2,
    float* __restrict__ x2sum, float* __restrict__ cnt,
    int E)
{
    int e = blockIdx.x * blockDim.x + threadIdx.x;
    if (e >= E) return;
    int r = ei[e];
    int c = ei[E + e];
    float in9[9];
    in9[0] = x[3 * r + 0]; in9[1] = x[3 * r + 1]; in9[2] = x[3 * r + 2];
    float xc0 = x[3 * c + 0], xc1 = x[3 * c + 1], xc2 = x[3 * c + 2];
    in9[3] = xc0; in9[4] = xc1; in9[5] = xc2;
    in9[6] = ea[3 * e + 0]; in9[7] = ea[3 * e + 1]; in9[8] = ea[3 * e + 2];
    float h[D2];
    #pragma unroll
    for (int j = 0; j < D2; ++j) {
        float a = eb1[j];
        #pragma unroll
        for (int k = 0; k < 9; ++k) a = fmaf(in9[k], ew1[k * D2 + j], a);
        h[j] = fmaxf(a, 0.0f);
    }
    float e2[D3];
    #pragma unroll
    for (int j = 0; j < D3; ++j) {
        float a = eb2[j];
        #pragma unroll
        for (int k = 0; k < D2; ++k) a = fmaf(h[k], ew2[k * D3 + j], a);
        e2[j] = a;
    }
    float h2[D2];
    #pragma unroll
    for (int j = 0; j < D2; ++j) {
        float a = nb1[j];
        a = fmaf(xc0, nw1[0 * D2 + j], a);
        a = fmaf(xc1, nw1[1 * D2 + j], a);
        a = fmaf(xc2, nw1[2 * D2 + j], a);
        #pragma unroll
        for (int k = 0; k < D3; ++k) a = fmaf(e2[k], nw1[(3 + k) * D2 + j], a);
        h2[j] = fmaxf(a, 0.0f);
    }
    float* dst = x2sum + (size_t)r * D3;
    #pragma unroll
    for (int j = 0; j < D3; ++j) {
        float a = nb2[j];
        #pragma unroll
        for (int k = 0; k < D2; ++k) a = fmaf(h2[k], nw2[k * D3 + j], a);
        atomicAdd(&dst[j], a);
    }
    atomicAdd(&cnt[r], 1.0f);
}

__global__ __launch_bounds__(256) void graph_sum_atomic_kernel(
    const float* __restrict__ x2sum, const float* __restrict__ cnt,
    const int* __restrict__ batch, int N,
    float* __restrict__ bx, float* __restrict__ brelu, float* __restrict__ ncnt)
{
    int b = blockIdx.x;
    int lo = 0, hi = N;
    while (lo < hi) { int m = (lo + hi) >> 1; if (batch[m] < b) lo = m + 1; else hi = m; }
    int start = lo;
    hi = N;
    while (lo < hi) { int m = (lo + hi) >> 1; if (batch[m] < b + 1) lo = m + 1; else hi = m; }
    int end = lo;
    float sx[D3], sr[D3];
    #pragma unroll
    for (int j = 0; j < D3; ++j) { sx[j] = 0.0f; sr[j] = 0.0f; }
    for (int i = start + (int)threadIdx.x; i < end; i += (int)blockDim.x) {
        float inv = 1.0f / fmaxf(cnt[i], 1.0f);
        #pragma unroll
        for (int j = 0; j < D3; ++j) {
            float v = x2sum[(size_t)i * D3 + j] * inv;
            sx[j] += v;
            sr[j] += fmaxf(v, 0.0f);
        }
    }
    #pragma unroll
    for (int j = 0; j < D3; ++j) {
        #pragma unroll
        for (int s = 32; s > 0; s >>= 1) {
            sx[j] += __shfl_down(sx[j], s);
            sr[j] += __shfl_down(sr[j], s);
        }
    }
    __shared__ float sm[4][2 * D3];
    int lane = threadIdx.x & 63, wid = threadIdx.x >> 6;
    if (lane == 0) {
        #pragma unroll
        for (int j = 0; j < D3; ++j) { sm[wid][j] = sx[j]; sm[wid][D3 + j] = sr[j]; }
    }
    __syncthreads();
    if (threadIdx.x < 2 * D3) {
        float v = sm[0][threadIdx.x] + sm[1][threadIdx.x] + sm[2][threadIdx.x] + sm[3][threadIdx.x];
        if (threadIdx.x < D3) bx[b * D3 + threadIdx.x] = v;
        else                  brelu[b * D3 + (threadIdx.x - D3)] = v;
    }
    if (threadIdx.x == 0) ncnt[b] = (float)(end - start);
}

extern "C" void kernel_launch(void* const* d_in, const int* in_sizes, int n_in,
                              void* d_out, int out_size, void* d_ws, size_t ws_size,
                              hipStream_t stream) {
    const float* x     = (const float*)d_in[0];
    const int*   ei    = (const int*)  d_in[1];
    const float* ea    = (const float*)d_in[2];
    const float* u     = (const float*)d_in[3];
    const int*   batch = (const int*)  d_in[4];
    const float* ew1 = (const float*)d_in[5];
    const float* eb1 = (const float*)d_in[6];
    const float* ew2 = (const float*)d_in[7];
    const float* eb2 = (const float*)d_in[8];
    const float* nw1 = (const float*)d_in[9];
    const float* nb1 = (const float*)d_in[10];
    const float* nw2 = (const float*)d_in[11];
    const float* nb2 = (const float*)d_in[12];
    const float* gw1 = (const float*)d_in[13];
    const float* gb1 = (const float*)d_in[14];
    const float* gw2 = (const float*)d_in[15];
    const float* gb2 = (const float*)d_in[16];
    const float* fc1w = (const float*)d_in[17];
    const float* fc1b = (const float*)d_in[18];
    const float* bng  = (const float*)d_in[19];
    const float* bnb  = (const float*)d_in[20];
    const float* fc2w = (const float*)d_in[21];
    const float* fc2b = (const float*)d_in[22];

    int N = in_sizes[0] / 3;
    int E = in_sizes[2] / 3;
    int B = in_sizes[3];
    float* out = (float*)d_out;

    int nsb = (N + SCAN_B - 1) / SCAN_B;   // scan blocks (391 for N=100K)

    // CSR-path workspace requirement
    size_t need = sizeof(int) * ((size_t)N /*deg*/ + (size_t)E /*rank*/ + (size_t)N /*base*/ + 1024 /*bsum*/)
                + sizeof(float) * ((size_t)E * D3 /*hbuf*/ + (size_t)N * D3 /*x2*/ + 2u * B * D3 + B);

    if (ws_size >= need && nsb <= 1024) {
        // ---- fast path: CSR build + atomic-free scatter ----
        char* p = (char*)d_ws;
        int* deg  = (int*)p;            p += sizeof(int) * (size_t)N;
        int* rank = (int*)p;            p += sizeof(int) * (size_t)E;
        int* base = (int*)p;            p += sizeof(int) * (size_t)N;
        int* bsum = (int*)p;            p += sizeof(int) * 1024;
        float* hbuf = (float*)p;        p += sizeof(float) * (size_t)E * D3;
        float* x2   = (float*)p;        p += sizeof(float) * (size_t)N * D3;
        float* bx    = (float*)p;       p += sizeof(float) * (size_t)B * D3;
        float* brelu = (float*)p;       p += sizeof(float) * (size_t)B * D3;
        float* ncnt  = (float*)p;

        hipMemsetAsync(deg, 0, sizeof(int) * (size_t)N, stream);

        int eb = (E + 255) / 256;
        deg_rank_kernel<<<eb, 256, 0, stream>>>(ei, deg, rank, E);

        scan1_kernel<<<nsb, SCAN_B, 0, stream>>>(deg, base, bsum, N);
        scan2_kernel<<<1, 1024, 0, stream>>>(bsum, nsb);
        scan3_kernel<<<nsb, SCAN_B, 0, stream>>>(base, bsum, N);

        edge_mlp_kernel<<<eb, 256, 0, stream>>>(
            x, ei, ea, ew1, eb1, ew2, eb2, nw1, nb1, nw2, nb2,
            base, rank, hbuf, E);

        int gtb = (N * D3 + 255) / 256;
        gather_kernel<<<gtb, 256, 0, stream>>>(hbuf, deg, base, x2, N);

        graph_sum_x2_kernel<<<B, 256, 0, stream>>>(x2, batch, N, bx, brelu, ncnt);

        int fb = (B + 255) / 256;
        final_kernel<<<fb, 256, 0, stream>>>(
            u, gw1, gb1, gw2, gb2, fc1w, fc1b, bng, bnb, fc2w, fc2b,
            bx, brelu, ncnt, out, B);
    } else {
        // ---- fallback: round-1 atomic path ----
        float* x2sum = (float*)d_ws;
        float* cnt   = x2sum + (size_t)N * D3;
        float* bx    = cnt + N;
        float* brelu = bx + (size_t)B * D3;
        float* ncnt  = brelu + (size_t)B * D3;

        hipMemsetAsync(x2sum, 0, sizeof(float) * ((size_t)N * D3 + N), stream);

        int eb = (E + 255) / 256;
        edge_node_atomic_kernel<<<eb, 256, 0, stream>>>(
            x, ei, ea, ew1, eb1, ew2, eb2, nw1, nb1, nw2, nb2, x2sum, cnt, E);

        graph_sum_atomic_kernel<<<B, 256, 0, stream>>>(x2sum, cnt, batch, N, bx, brelu, ncnt);

        int fb = (B + 255) / 256;
        final_kernel<<<fb, 256, 0, stream>>>(
            u, gw1, gb1, gw2, gb2, fc1w, fc1b, bng, bnb, fc2w, fc2b,
            bx, brelu, ncnt, out, B);
    }
}

// Round 3
// 537.356 us; speedup vs baseline: 2.5273x; 1.0010x over previous
//
#include <hip/hip_runtime.h>
#include <math.h>

#define D1 3
#define D2 50
#define D3 15
#define D5 10
#define NC 6
#define SCAN_B 256

// ---------------------------------------------------------------------------
// Kernel A: degree + rank. One int atomic per edge; return value = rank of
// this edge within its destination node. 16x fewer atomics than round 1.
// ---------------------------------------------------------------------------
__global__ __launch_bounds__(256) void deg_rank_kernel(
    const int* __restrict__ ei, int* __restrict__ deg, int* __restrict__ rank, int E)
{
    int e = blockIdx.x * blockDim.x + threadIdx.x;
    if (e >= E) return;
    int r = ei[e];
    rank[e] = atomicAdd(&deg[r], 1);
}

// ---------------------------------------------------------------------------
// Exclusive scan of deg[N] -> base[N], 3-phase.
// ---------------------------------------------------------------------------
__global__ __launch_bounds__(SCAN_B) void scan1_kernel(
    const int* __restrict__ deg, int* __restrict__ base, int* __restrict__ bsum, int N)
{
    __shared__ int sm[SCAN_B];
    int i = blockIdx.x * SCAN_B + threadIdx.x;
    int v = (i < N) ? deg[i] : 0;
    sm[threadIdx.x] = v;
    __syncthreads();
    #pragma unroll
    for (int s = 1; s < SCAN_B; s <<= 1) {
        int t = (threadIdx.x >= s) ? sm[threadIdx.x - s] : 0;
        __syncthreads();
        sm[threadIdx.x] += t;
        __syncthreads();
    }
    if (i < N) base[i] = sm[threadIdx.x] - v;   // exclusive
    if (threadIdx.x == SCAN_B - 1) bsum[blockIdx.x] = sm[threadIdx.x];
}

__global__ __launch_bounds__(1024) void scan2_kernel(int* __restrict__ bsum, int nb)
{
    __shared__ int sm[1024];
    int v = ((int)threadIdx.x < nb) ? bsum[threadIdx.x] : 0;
    sm[threadIdx.x] = v;
    __syncthreads();
    #pragma unroll
    for (int s = 1; s < 1024; s <<= 1) {
        int t = (threadIdx.x >= s) ? sm[threadIdx.x - s] : 0;
        __syncthreads();
        sm[threadIdx.x] += t;
        __syncthreads();
    }
    if ((int)threadIdx.x < nb) bsum[threadIdx.x] = sm[threadIdx.x] - v; // exclusive
}

__global__ __launch_bounds__(SCAN_B) void scan3_kernel(
    int* __restrict__ base, const int* __restrict__ bsum, int N)
{
    int i = blockIdx.x * SCAN_B + threadIdx.x;
    if (i < N) base[i] += bsum[blockIdx.x];
}

// ---------------------------------------------------------------------------
// Kernel C: fused edge MLP + node MLP per edge, NO atomics. Writes the 15
// node-MLP outputs to hbuf at the CSR slot base[row]+rank[e].
// Weights read wave-uniformly -> s_load -> each MAC is one v_fmac.
// ---------------------------------------------------------------------------
__global__ __launch_bounds__(256) void edge_mlp_kernel(
    const float* __restrict__ x,
    const int*   __restrict__ ei,
    const float* __restrict__ ea,
    const float* __restrict__ ew1, const float* __restrict__ eb1,
    const float* __restrict__ ew2, const float* __restrict__ eb2,
    const float* __restrict__ nw1, const float* __restrict__ nb1,
    const float* __restrict__ nw2, const float* __restrict__ nb2,
    const int* __restrict__ base, const int* __restrict__ rank,
    float* __restrict__ hbuf,
    int E)
{
    int e = blockIdx.x * blockDim.x + threadIdx.x;
    if (e >= E) return;

    int r = ei[e];
    int c = ei[E + e];

    float in9[9];
    in9[0] = x[3 * r + 0];
    in9[1] = x[3 * r + 1];
    in9[2] = x[3 * r + 2];
    float xc0 = x[3 * c + 0], xc1 = x[3 * c + 1], xc2 = x[3 * c + 2];
    in9[3] = xc0; in9[4] = xc1; in9[5] = xc2;
    in9[6] = ea[3 * e + 0];
    in9[7] = ea[3 * e + 1];
    in9[8] = ea[3 * e + 2];

    // edge MLP layer 1: 9 -> 50, ReLU
    float h[D2];
    #pragma unroll
    for (int j = 0; j < D2; ++j) {
        float a = eb1[j];
        #pragma unroll
        for (int k = 0; k < 9; ++k) a = fmaf(in9[k], ew1[k * D2 + j], a);
        h[j] = fmaxf(a, 0.0f);
    }

    // edge MLP layer 2: 50 -> 15
    float e2[D3];
    #pragma unroll
    for (int j = 0; j < D3; ++j) {
        float a = eb2[j];
        #pragma unroll
        for (int k = 0; k < D2; ++k) a = fmaf(h[k], ew2[k * D3 + j], a);
        e2[j] = a;
    }

    // node MLP layer 1: [x[col], e2] (18) -> 50, ReLU
    float h2[D2];
    #pragma unroll
    for (int j = 0; j < D2; ++j) {
        float a = nb1[j];
        a = fmaf(xc0, nw1[0 * D2 + j], a);
        a = fmaf(xc1, nw1[1 * D2 + j], a);
        a = fmaf(xc2, nw1[2 * D2 + j], a);
        #pragma unroll
        for (int k = 0; k < D3; ++k) a = fmaf(e2[k], nw1[(3 + k) * D2 + j], a);
        h2[j] = fmaxf(a, 0.0f);
    }

    // node MLP layer 2: 50 -> 15, plain store to CSR slot
    int slot = base[r] + rank[e];
    float* dst = hbuf + (size_t)slot * D3;
    #pragma unroll
    for (int j = 0; j < D3; ++j) {
        float a = nb2[j];
        #pragma unroll
        for (int k = 0; k < D2; ++k) a = fmaf(h2[k], nw2[k * D3 + j], a);
        dst[j] = a;
    }
}

// ---------------------------------------------------------------------------
// Kernel D: CSR gather. Thread = (node, dim). Sums hbuf over the node's
// contiguous segment, divides by max(deg,1) -> x2.
// ---------------------------------------------------------------------------
__global__ __launch_bounds__(256) void gather_kernel(
    const float* __restrict__ hbuf, const int* __restrict__ deg,
    const int* __restrict__ base, float* __restrict__ x2, int N)
{
    int idx = blockIdx.x * blockDim.x + threadIdx.x;
    if (idx >= N * D3) return;
    int n = idx / D3;
    int j = idx - n * D3;
    int b = base[n];
    int d = deg[n];
    float s = 0.0f;
    for (int k = 0; k < d; ++k) s += hbuf[(size_t)(b + k) * D3 + j];
    x2[(size_t)n * D3 + j] = s / fmaxf((float)d, 1.0f);
}

// ---------------------------------------------------------------------------
// Kernel E: per-graph sums of x2 and relu(x2). batch sorted -> contiguous
// ranges via binary search; one block per graph.
// ---------------------------------------------------------------------------
__global__ __launch_bounds__(256) void graph_sum_x2_kernel(
    const float* __restrict__ x2,
    const int* __restrict__ batch, int N,
    float* __restrict__ bx, float* __restrict__ brelu, float* __restrict__ ncnt)
{
    int b = blockIdx.x;

    int lo = 0, hi = N;
    while (lo < hi) { int m = (lo + hi) >> 1; if (batch[m] < b) lo = m + 1; else hi = m; }
    int start = lo;
    hi = N;
    while (lo < hi) { int m = (lo + hi) >> 1; if (batch[m] < b + 1) lo = m + 1; else hi = m; }
    int end = lo;

    float sx[D3], sr[D3];
    #pragma unroll
    for (int j = 0; j < D3; ++j) { sx[j] = 0.0f; sr[j] = 0.0f; }

    for (int i = start + (int)threadIdx.x; i < end; i += (int)blockDim.x) {
        #pragma unroll
        for (int j = 0; j < D3; ++j) {
            float v = x2[(size_t)i * D3 + j];
            sx[j] += v;
            sr[j] += fmaxf(v, 0.0f);
        }
    }

    #pragma unroll
    for (int j = 0; j < D3; ++j) {
        #pragma unroll
        for (int s = 32; s > 0; s >>= 1) {
            sx[j] += __shfl_down(sx[j], s);
            sr[j] += __shfl_down(sr[j], s);
        }
    }

    __shared__ float sm[4][2 * D3];
    int lane = threadIdx.x & 63, wid = threadIdx.x >> 6;
    if (lane == 0) {
        #pragma unroll
        for (int j = 0; j < D3; ++j) { sm[wid][j] = sx[j]; sm[wid][D3 + j] = sr[j]; }
    }
    __syncthreads();
    if (threadIdx.x < 2 * D3) {
        float v = sm[0][threadIdx.x] + sm[1][threadIdx.x] + sm[2][threadIdx.x] + sm[3][threadIdx.x];
        if (threadIdx.x < D3) bx[b * D3 + threadIdx.x] = v;
        else                  brelu[b * D3 + (threadIdx.x - D3)] = v;
    }
    if (threadIdx.x == 0) ncnt[b] = (float)(end - start);
}

// ---------------------------------------------------------------------------
// Kernel F: global MLP + readout mean + FC head + BN(eval) + log_softmax.
// ---------------------------------------------------------------------------
__global__ __launch_bounds__(256) void final_kernel(
    const float* __restrict__ u,
    const float* __restrict__ gw1, const float* __restrict__ gb1,
    const float* __restrict__ gw2, const float* __restrict__ gb2,
    const float* __restrict__ fc1w, const float* __restrict__ fc1b,
    const float* __restrict__ bng, const float* __restrict__ bnb,
    const float* __restrict__ fc2w, const float* __restrict__ fc2b,
    const float* __restrict__ bx, const float* __restrict__ brelu,
    const float* __restrict__ ncnt,
    float* __restrict__ out, int B)
{
    int t = blockIdx.x * blockDim.x + threadIdx.x;
    if (t >= B) return;

    float nct = ncnt[t];
    float inv = 1.0f / fmaxf(nct, 1.0f);

    float in16[16];
    in16[0] = u[t];
    #pragma unroll
    for (int j = 0; j < D3; ++j) in16[1 + j] = bx[t * D3 + j] * inv;

    float gh[D2];
    #pragma unroll
    for (int j = 0; j < D2; ++j) {
        float a = gb1[j];
        #pragma unroll
        for (int k = 0; k < 16; ++k) a = fmaf(in16[k], gw1[k * D2 + j], a);
        gh[j] = fmaxf(a, 0.0f);
    }

    float g[D3];
    #pragma unroll
    for (int j = 0; j < D3; ++j) {
        float a = gb2[j];
        #pragma unroll
        for (int k = 0; k < D2; ++k) a = fmaf(gh[k], gw2[k * D3 + j], a);
        g[j] = (brelu[t * D3 + j] + fmaxf(a, 0.0f)) / (nct + 1.0f);
    }

    const float bnscale = 1.0f / sqrtf(1.0f + 1e-5f);
    float h1[D5];
    #pragma unroll
    for (int i = 0; i < D5; ++i) {
        float a = fc1b[i];
        #pragma unroll
        for (int k = 0; k < D3; ++k) a = fmaf(g[k], fc1w[k * D5 + i], a);
        h1[i] = fmaxf(a * (bng[i] * bnscale) + bnb[i], 0.0f);
    }

    float o[NC];
    #pragma unroll
    for (int j = 0; j < NC; ++j) {
        float a = fc2b[j];
        #pragma unroll
        for (int k = 0; k < D5; ++k) a = fmaf(h1[k], fc2w[k * NC + j], a);
        o[j] = a;
    }
    float m = o[0];
    #pragma unroll
    for (int j = 1; j < NC; ++j) m = fmaxf(m, o[j]);
    float ssum = 0.0f;
    #pragma unroll
    for (int j = 0; j < NC; ++j) ssum += expf(o[j] - m);
    float lse = m + logf(ssum);
    #pragma unroll
    for (int j = 0; j < NC; ++j) out[t * NC + j] = o[j] - lse;
}

// ---------------------------------------------------------------------------
// Fallback (round-1) kernels: atomic scatter-mean. Used only if ws too small.
// ---------------------------------------------------------------------------
__global__ __launch_bounds__(256) void edge_node_atomic_kernel(
    const float* __restrict__ x,
    const int*   __restrict__ ei,
    const float* __restrict__ ea,
    const float* __restrict__ ew1, const float* __restrict__ eb1,
    const float* __restrict__ ew2, const float* __restrict__ eb2,
    const float* __restrict__ nw1, const float* __restrict__ nb1,
    const float* __restrict__ nw2, const float* __restrict__ nb2,
    float* __restrict__ x2sum, float* __restrict__ cnt,
    int E)
{
    int e = blockIdx.x * blockDim.x + threadIdx.x;
    if (e >= E) return;
    int r = ei[e];
    int c = ei[E + e];
    float in9[9];
    in9[0] = x[3 * r + 0]; in9[1] = x[3 * r + 1]; in9[2] = x[3 * r + 2];
    float xc0 = x[3 * c + 0], xc1 = x[3 * c + 1], xc2 = x[3 * c + 2];
    in9[3] = xc0; in9[4] = xc1; in9[5] = xc2;
    in9[6] = ea[3 * e + 0]; in9[7] = ea[3 * e + 1]; in9[8] = ea[3 * e + 2];
    float h[D2];
    #pragma unroll
    for (int j = 0; j < D2; ++j) {
        float a = eb1[j];
        #pragma unroll
        for (int k = 0; k < 9; ++k) a = fmaf(in9[k], ew1[k * D2 + j], a);
        h[j] = fmaxf(a, 0.0f);
    }
    float e2[D3];
    #pragma unroll
    for (int j = 0; j < D3; ++j) {
        float a = eb2[j];
        #pragma unroll
        for (int k = 0; k < D2; ++k) a = fmaf(h[k], ew2[k * D3 + j], a);
        e2[j] = a;
    }
    float h2[D2];
    #pragma unroll
    for (int j = 0; j < D2; ++j) {
        float a = nb1[j];
        a = fmaf(xc0, nw1[0 * D2 + j], a);
        a = fmaf(xc1, nw1[1 * D2 + j], a);
        a = fmaf(xc2, nw1[2 * D2 + j], a);
        #pragma unroll
        for (int k = 0; k < D3; ++k) a = fmaf(e2[k], nw1[(3 + k) * D2 + j], a);
        h2[j] = fmaxf(a, 0.0f);
    }
    float* dst = x2sum + (size_t)r * D3;
    #pragma unroll
    for (int j = 0; j < D3; ++j) {
        float a = nb2[j];
        #pragma unroll
        for (int k = 0; k < D2; ++k) a = fmaf(h2[k], nw2[k * D3 + j], a);
        atomicAdd(&dst[j], a);
    }
    atomicAdd(&cnt[r], 1.0f);
}

__global__ __launch_bounds__(256) void graph_sum_atomic_kernel(
    const float* __restrict__ x2sum, const float* __restrict__ cnt,
    const int* __restrict__ batch, int N,
    float* __restrict__ bx, float* __restrict__ brelu, float* __restrict__ ncnt)
{
    int b = blockIdx.x;
    int lo = 0, hi = N;
    while (lo < hi) { int m = (lo + hi) >> 1; if (batch[m] < b) lo = m + 1; else hi = m; }
    int start = lo;
    hi = N;
    while (lo < hi) { int m = (lo + hi) >> 1; if (batch[m] < b + 1) lo = m + 1; else hi = m; }
    int end = lo;
    float sx[D3], sr[D3];
    #pragma unroll
    for (int j = 0; j < D3; ++j) { sx[j] = 0.0f; sr[j] = 0.0f; }
    for (int i = start + (int)threadIdx.x; i < end; i += (int)blockDim.x) {
        float inv = 1.0f / fmaxf(cnt[i], 1.0f);
        #pragma unroll
        for (int j = 0; j < D3; ++j) {
            float v = x2sum[(size_t)i * D3 + j] * inv;
            sx[j] += v;
            sr[j] += fmaxf(v, 0.0f);
        }
    }
    #pragma unroll
    for (int j = 0; j < D3; ++j) {
        #pragma unroll
        for (int s = 32; s > 0; s >>= 1) {
            sx[j] += __shfl_down(sx[j], s);
            sr[j] += __shfl_down(sr[j], s);
        }
    }
    __shared__ float sm[4][2 * D3];
    int lane = threadIdx.x & 63, wid = threadIdx.x >> 6;
    if (lane == 0) {
        #pragma unroll
        for (int j = 0; j < D3; ++j) { sm[wid][j] = sx[j]; sm[wid][D3 + j] = sr[j]; }
    }
    __syncthreads();
    if (threadIdx.x < 2 * D3) {
        float v = sm[0][threadIdx.x] + sm[1][threadIdx.x] + sm[2][threadIdx.x] + sm[3][threadIdx.x];
        if (threadIdx.x < D3) bx[b * D3 + threadIdx.x] = v;
        else                  brelu[b * D3 + (threadIdx.x - D3)] = v;
    }
    if (threadIdx.x == 0) ncnt[b] = (float)(end - start);
}

extern "C" void kernel_launch(void* const* d_in, const int* in_sizes, int n_in,
                              void* d_out, int out_size, void* d_ws, size_t ws_size,
                              hipStream_t stream) {
    const float* x     = (const float*)d_in[0];
    const int*   ei    = (const int*)  d_in[1];
    const float* ea    = (const float*)d_in[2];
    const float* u     = (const float*)d_in[3];
    const int*   batch = (const int*)  d_in[4];
    const float* ew1 = (const float*)d_in[5];
    const float* eb1 = (const float*)d_in[6];
    const float* ew2 = (const float*)d_in[7];
    const float* eb2 = (const float*)d_in[8];
    const float* nw1 = (const float*)d_in[9];
    const float* nb1 = (const float*)d_in[10];
    const float* nw2 = (const float*)d_in[11];
    const float* nb2 = (const float*)d_in[12];
    const float* gw1 = (const float*)d_in[13];
    const float* gb1 = (const float*)d_in[14];
    const float* gw2 = (const float*)d_in[15];
    const float* gb2 = (const float*)d_in[16];
    const float* fc1w = (const float*)d_in[17];
    const float* fc1b = (const float*)d_in[18];
    const float* bng  = (const float*)d_in[19];
    const float* bnb  = (const float*)d_in[20];
    const float* fc2w = (const float*)d_in[21];
    const float* fc2b = (const float*)d_in[22];

    int N = in_sizes[0] / 3;
    int E = in_sizes[2] / 3;
    int B = in_sizes[3];
    float* out = (float*)d_out;

    int nsb = (N + SCAN_B - 1) / SCAN_B;   // scan blocks (391 for N=100K)

    // CSR-path workspace requirement
    size_t need = sizeof(int) * ((size_t)N /*deg*/ + (size_t)E /*rank*/ + (size_t)N /*base*/ + 1024 /*bsum*/)
                + sizeof(float) * ((size_t)E * D3 /*hbuf*/ + (size_t)N * D3 /*x2*/ + 2u * B * D3 + B);

    if (ws_size >= need && nsb <= 1024) {
        // ---- fast path: CSR build + atomic-free scatter ----
        char* p = (char*)d_ws;
        int* deg  = (int*)p;            p += sizeof(int) * (size_t)N;
        int* rank = (int*)p;            p += sizeof(int) * (size_t)E;
        int* base = (int*)p;            p += sizeof(int) * (size_t)N;
        int* bsum = (int*)p;            p += sizeof(int) * 1024;
        float* hbuf = (float*)p;        p += sizeof(float) * (size_t)E * D3;
        float* x2   = (float*)p;        p += sizeof(float) * (size_t)N * D3;
        float* bx    = (float*)p;       p += sizeof(float) * (size_t)B * D3;
        float* brelu = (float*)p;       p += sizeof(float) * (size_t)B * D3;
        float* ncnt  = (float*)p;

        hipMemsetAsync(deg, 0, sizeof(int) * (size_t)N, stream);

        int eb = (E + 255) / 256;
        deg_rank_kernel<<<eb, 256, 0, stream>>>(ei, deg, rank, E);

        scan1_kernel<<<nsb, SCAN_B, 0, stream>>>(deg, base, bsum, N);
        scan2_kernel<<<1, 1024, 0, stream>>>(bsum, nsb);
        scan3_kernel<<<nsb, SCAN_B, 0, stream>>>(base, bsum, N);

        edge_mlp_kernel<<<eb, 256, 0, stream>>>(
            x, ei, ea, ew1, eb1, ew2, eb2, nw1, nb1, nw2, nb2,
            base, rank, hbuf, E);

        int gtb = (N * D3 + 255) / 256;
        gather_kernel<<<gtb, 256, 0, stream>>>(hbuf, deg, base, x2, N);

        graph_sum_x2_kernel<<<B, 256, 0, stream>>>(x2, batch, N, bx, brelu, ncnt);

        int fb = (B + 255) / 256;
        final_kernel<<<fb, 256, 0, stream>>>(
            u, gw1, gb1, gw2, gb2, fc1w, fc1b, bng, bnb, fc2w, fc2b,
            bx, brelu, ncnt, out, B);
    } else {
        // ---- fallback: round-1 atomic path ----
        float* x2sum = (float*)d_ws;
        float* cnt   = x2sum + (size_t)N * D3;
        float* bx    = cnt + N;
        float* brelu = bx + (size_t)B * D3;
        float* ncnt  = brelu + (size_t)B * D3;

        hipMemsetAsync(x2sum, 0, sizeof(float) * ((size_t)N * D3 + N), stream);

        int eb = (E + 255) / 256;
        edge_node_atomic_kernel<<<eb, 256, 0, stream>>>(
            x, ei, ea, ew1, eb1, ew2, eb2, nw1, nb1, nw2, nb2, x2sum, cnt, E);

        graph_sum_atomic_kernel<<<B, 256, 0, stream>>>(x2sum, cnt, batch, N, bx, brelu, ncnt);

        int fb = (B + 255) / 256;
        final_kernel<<<fb, 256, 0, stream>>>(
            u, gw1, gb1, gw2, gb2, fc1w, fc1b, bng, bnb, fc2w, fc2b,
            bx, brelu, ncnt, out, B);
    }
}